// Round 6
// baseline (459.381 us; speedup 1.0000x reference)
//
#include <hip/hip_runtime.h>
#include <cmath>

typedef __bf16 bf16;
typedef short bf16x8 __attribute__((ext_vector_type(8)));   // MFMA A/B fragment (bf16 bit patterns)
typedef __bf16 bf16v8 __attribute__((ext_vector_type(8)));  // arithmetic bf16 vector
typedef __bf16 bf16v4 __attribute__((ext_vector_type(4)));
typedef float f32x4 __attribute__((ext_vector_type(4)));
typedef float f32x16 __attribute__((ext_vector_type(16)));

// async global->LDS, 16B per lane. LDS base must be wave-uniform; HW adds lane*16.
__device__ __forceinline__ void load_lds16(const void* g, void* l) {
    __builtin_amdgcn_global_load_lds(
        (const __attribute__((address_space(1))) void*)g,
        (__attribute__((address_space(3))) void*)l, 16, 0, 0);
}

__device__ __forceinline__ unsigned pack_bf16x2(float a, float b) {
    union { bf16 h[2]; unsigned u; } t;
    t.h[0] = (bf16)a;
    t.h[1] = (bf16)b;
    return t.u;
}

// ---------------------------------------------------------------------------
// Fused prep: 1D grid, block ranges:
// [0,8192)        x f32 -> xb bf16          (8388608 elems)
// [8192,20480)    wq/wk/wv transpose+cvt -> wT[z]   (3 x 64x64 tiles)
// [20480,24576)   wo f32 -> wob bf16        (4194304 elems)
// [24576,24580)   xn -> xnb                 (4096 elems)
__global__ __launch_bounds__(256) void k_prep(
    const float* __restrict__ x, const float* __restrict__ xn,
    const float* __restrict__ wq, const float* __restrict__ wk,
    const float* __restrict__ wv, const float* __restrict__ wo,
    bf16* __restrict__ xb, bf16* __restrict__ xnb, bf16* __restrict__ wT,
    bf16* __restrict__ wob, float qscale) {
    __shared__ float tile[32][33];
    const int bid = blockIdx.x, tid = threadIdx.x;
    if (bid < 8192) {
        int i = bid * 1024 + tid * 4;
        float4 v = *(const float4*)(x + i);
        bf16v4 o;
        o[0] = (bf16)v.x; o[1] = (bf16)v.y; o[2] = (bf16)v.z; o[3] = (bf16)v.w;
        *(bf16v4*)(xb + i) = o;
    } else if (bid < 20480) {
        const int r = bid - 8192;
        const int z = r >> 12, rr = r & 4095;
        const float* w = z == 0 ? wq : z == 1 ? wk : wv;
        bf16* wt = wT + (size_t)z * 4194304;
        const float scale = z == 0 ? qscale : 1.f;
        const int tx = tid & 31, ty = tid >> 5;  // 32 x 8
        const int k0 = (rr & 63) * 32, n0 = (rr >> 6) * 32;
#pragma unroll
        for (int i = 0; i < 4; i++) {
            int kk = ty + i * 8;
            tile[kk][tx] = w[(size_t)(k0 + kk) * 2048 + n0 + tx];
        }
        __syncthreads();
#pragma unroll
        for (int i = 0; i < 4; i++) {
            int nn = ty + i * 8;
            wt[(size_t)(n0 + nn) * 2048 + k0 + tx] = (bf16)(tile[tx][nn] * scale);
        }
    } else if (bid < 24576) {
        int i = (bid - 20480) * 1024 + tid * 4;
        float4 v = *(const float4*)(wo + i);
        bf16v4 o;
        o[0] = (bf16)v.x; o[1] = (bf16)v.y; o[2] = (bf16)v.z; o[3] = (bf16)v.w;
        *(bf16v4*)(wob + i) = o;
    } else {
        int i = (bid - 24576) * 1024 + tid * 4;
        float4 v = *(const float4*)(xn + i);
        bf16v4 o;
        o[0] = (bf16)v.x; o[1] = (bf16)v.y; o[2] = (bf16)v.z; o[3] = (bf16)v.w;
        *(bf16v4*)(xnb + i) = o;
    }
}

// ---------------------------------------------------------------------------
// Fused QKV GEMM + decode QKV GEMV.
// bid<1536: 128x128 tile GEMM A[4096][2048] x Bt[6144][2048]^T (m-fastest).
//   LDS chunk-swizzled (chunk = quad ^ ((row>>1)&3)) -> conflict-free b128.
//   n0<2048 -> Q; <4096 -> K; else V written transposed to Vt[b][nh][s].
// bid>=1536 (16 blocks): decode GEMV q1/k1/v1 = xnb x W^T (both batches).
__global__ __launch_bounds__(256) void k_gemm_qkv(
    const bf16* __restrict__ A, const bf16* __restrict__ Bt,
    bf16* __restrict__ Qo, bf16* __restrict__ Ko, bf16* __restrict__ Vto,
    const bf16* __restrict__ xnb, bf16* __restrict__ q1,
    bf16* __restrict__ k1, bf16* __restrict__ v1) {
    const int K = 2048;
    __shared__ __align__(16) bf16 sA[128 * 32];
    __shared__ __align__(16) bf16 sB[128 * 32];
    const int bid = blockIdx.x;
    const int tid = threadIdx.x;
    if (bid >= 1536) {
        // ---- decode GEMV: 64 waves over 6144 (z,n) rows, both b at once ----
        const int wave = tid >> 6, lane = tid & 63;
        const int w0 = (bid - 1536) * 4 + wave;
        for (int u = w0; u < 6144; u += 64) {
            const int z = u >> 11, n = u & 2047;
            const bf16* wr = Bt + (size_t)z * 4194304 + (size_t)n * 2048;
            float s0 = 0.f, s1 = 0.f;
#pragma unroll
            for (int i = 0; i < 4; i++) {
                int k = i * 512 + lane * 8;
                bf16v8 wv8 = *(const bf16v8*)(wr + k);
                bf16v8 x0 = *(const bf16v8*)(xnb + k);
                bf16v8 x1 = *(const bf16v8*)(xnb + 2048 + k);
#pragma unroll
                for (int j = 0; j < 8; j++) {
                    float wj = (float)wv8[j];
                    s0 += (float)x0[j] * wj;
                    s1 += (float)x1[j] * wj;
                }
            }
#pragma unroll
            for (int off = 1; off <= 32; off <<= 1) {
                s0 += __shfl_xor(s0, off);
                s1 += __shfl_xor(s1, off);
            }
            if (lane == 0) {
                bf16* y = z == 0 ? q1 : z == 1 ? k1 : v1;
                y[n] = (bf16)s0;
                y[2048 + n] = (bf16)s1;
            }
        }
        return;
    }
    const int wave = tid >> 6, lane = tid & 63;
    const int quad = lane >> 4, l15 = lane & 15;
    const int rsw = (l15 >> 1) & 3;  // == (row>>1)&3 for all frag rows
    const int wm = (wave >> 1) * 64, wn = (wave & 1) * 64;
    const int m0 = (bid & 31) * 128, n0 = (bid >> 5) * 128;

    f32x4 acc[4][4];
#pragma unroll
    for (int a = 0; a < 4; a++)
#pragma unroll
        for (int c = 0; c < 4; c++)
#pragma unroll
            for (int r = 0; r < 4; r++) acc[a][c][r] = 0.f;

    for (int k0 = 0; k0 < K; k0 += 32) {
        __syncthreads();
#pragma unroll
        for (int i = 0; i < 2; i++) {
            const int slotBase = wave * 128 + i * 64;
            const int slot = slotBase + lane;
            const int row = slot >> 2, cp = slot & 3;
            const int g = cp ^ ((row >> 1) & 3);  // swizzle: LDS chunk cp holds global chunk g
            load_lds16(A + (size_t)(m0 + row) * K + k0 + g * 8, &sA[slotBase * 8]);
            load_lds16(Bt + (size_t)(n0 + row) * K + k0 + g * 8, &sB[slotBase * 8]);
        }
        __syncthreads();
        bf16x8 af[4], bfr[4];
#pragma unroll
        for (int t = 0; t < 4; t++) {
            af[t] = *(const bf16x8*)(sA + (wm + t * 16 + l15) * 32 + (quad ^ rsw) * 8);
            bfr[t] = *(const bf16x8*)(sB + (wn + t * 16 + l15) * 32 + (quad ^ rsw) * 8);
        }
#pragma unroll
        for (int mi = 0; mi < 4; mi++)
#pragma unroll
            for (int ni = 0; ni < 4; ni++)
                acc[mi][ni] = __builtin_amdgcn_mfma_f32_16x16x32_bf16(
                    af[mi], bfr[ni], acc[mi][ni], 0, 0, 0);
    }

    if (n0 < 4096) {
        bf16* Co = n0 < 2048 ? Qo : Ko;
        const int nb = n0 & 2047;
#pragma unroll
        for (int mi = 0; mi < 4; mi++)
#pragma unroll
            for (int ni = 0; ni < 4; ni++)
#pragma unroll
                for (int r = 0; r < 4; r++) {
                    int row = m0 + wm + mi * 16 + quad * 4 + r;
                    int col = nb + wn + ni * 16 + l15;
                    Co[(size_t)row * 2048 + col] = (bf16)acc[mi][ni][r];
                }
    } else {
        const int nb = n0 - 4096;
        const int b = m0 >> 11, s0v = m0 & 2047;
#pragma unroll
        for (int mi = 0; mi < 4; mi++)
#pragma unroll
            for (int ni = 0; ni < 4; ni++) {
                const int nh = nb + wn + ni * 16 + l15;
                bf16v4 o4;
#pragma unroll
                for (int r = 0; r < 4; r++) o4[r] = (bf16)acc[mi][ni][r];
                *(bf16v4*)(Vto + (size_t)(b * 2048 + nh) * 2048 + s0v + wm +
                           mi * 16 + quad * 4) = o4;
            }
    }
}

// ---------------------------------------------------------------------------
// Flash-style causal prefill attention v5 (kappa-permuted keys) + folded
// split-K decode phase 1 (bid>=512).
__global__ __launch_bounds__(256, 2) void k_attn(
    const bf16* __restrict__ Q, const bf16* __restrict__ Kc,
    const bf16* __restrict__ Vt, bf16* __restrict__ O,
    const bf16* __restrict__ q1, float* __restrict__ pm,
    float* __restrict__ pl, float* __restrict__ pacc) {
    __shared__ __align__(16) bf16 sK[128 * 128];
    __shared__ __align__(16) bf16 sV[128 * 128];
    const int tid = threadIdx.x;

    if (blockIdx.x >= 512) {
        // ---- decode split-K phase 1: r -> (head, b, split), 256 keys ----
        __shared__ __align__(16) bf16 sq[128];
        __shared__ float scd[256];
        __shared__ float red[4];
        __shared__ float ph[256];
        const int r = blockIdx.x - 512;
        const int head = r & 15, b = (r >> 4) & 1, sp = r >> 5;
        const int s0 = sp * 256;
        const int lane = tid & 63, wave = tid >> 6;
        const int idx = (b * 16 + head) * 8 + sp;

        if (tid < 16)
            *(uint4*)(sq + tid * 8) =
                *(const uint4*)(q1 + (size_t)b * 2048 + head * 128 + tid * 8);
        __syncthreads();

        const bf16* kr = Kc + (size_t)(b * 2048 + s0 + tid) * 2048 + head * 128;
        float s = 0.f;
#pragma unroll
        for (int k = 0; k < 128; k += 8) {
            bf16v8 kv = *(const bf16v8*)(kr + k);
            bf16v8 qv = *(const bf16v8*)(sq + k);
#pragma unroll
            for (int j = 0; j < 8; j++) s += (float)qv[j] * (float)kv[j];
        }
        float m = s;
#pragma unroll
        for (int off = 1; off <= 32; off <<= 1) m = fmaxf(m, __shfl_xor(m, off));
        if (lane == 0) red[wave] = m;
        __syncthreads();
        const float gm = fmaxf(fmaxf(red[0], red[1]), fmaxf(red[2], red[3]));
        float p = __builtin_amdgcn_exp2f(s - gm);
        scd[tid] = p;
        float ls = p;
#pragma unroll
        for (int off = 1; off <= 32; off <<= 1) ls += __shfl_xor(ls, off);
        __syncthreads();
        if (lane == 0) red[wave] = ls;
        __syncthreads();
        if (tid == 0) {
            pm[idx] = gm;
            pl[idx] = red[0] + red[1] + red[2] + red[3];
        }
        const int h = tid & 127, halfk = tid >> 7;
        const bf16* vr =
            Vt + (size_t)(b * 2048 + head * 128 + h) * 2048 + s0 + halfk * 128;
        float acc = 0.f;
#pragma unroll
        for (int t = 0; t < 128; t += 8) {
            bf16v8 vv = *(const bf16v8*)(vr + t);
#pragma unroll
            for (int j = 0; j < 8; j++) acc += scd[halfk * 128 + t + j] * (float)vv[j];
        }
        ph[tid] = acc;
        __syncthreads();
        if (halfk == 0) pacc[(size_t)idx * 128 + h] = ph[tid] + ph[tid + 128];
        return;
    }

    const int wave = tid >> 6, lane = tid & 63;
    const int l31 = lane & 31, half = lane >> 5;
    const int lin = blockIdx.x;
    const int bb = lin >> 8;
    const int idx = lin & 255;
    const int T = bb ? (15 - (idx & 15)) : (idx & 15);
    const int head = idx >> 4;
    const int qb = T * 128;
    const int nkt = T + 1;

    const bf16* Kbase = Kc + (size_t)(bb * 2048) * 2048 + head * 128;
    const bf16* Vbase = Vt + (size_t)(bb * 2048 + head * 128) * 2048;
    const int swzA = l31 & 7;

    const int query_l = wave * 32 + l31;
    const bf16* Qrow = Q + (size_t)(bb * 2048 + qb + query_l) * 2048 + head * 128;
    bf16x8 qf[8];
#pragma unroll
    for (int kc = 0; kc < 8; kc++)
        qf[kc] = *(const bf16x8*)(Qrow + kc * 16 + half * 8);

    f32x16 accO[4];
#pragma unroll
    for (int ht = 0; ht < 4; ht++)
#pragma unroll
        for (int g = 0; g < 16; g++) accO[ht][g] = 0.f;
    float m_i = -INFINITY, l_i = 0.f;
    const int query_g = qb + query_l;

    for (int kt = 0; kt < nkt; ++kt) {
        const int t0 = kt * 128;
        __syncthreads();
#pragma unroll
        for (int i = 0; i < 8; ++i) {
            const int slotBase = wave * 512 + i * 64;
            const int slot = slotBase + lane;
            const int rw = slot >> 4, cp = slot & 15;
            const int c = cp ^ (rw & 7);
            const int krw = (rw & ~12) | ((rw & 4) << 1) | ((rw & 8) >> 1);  // kappa
            load_lds16(Kbase + (size_t)(t0 + krw) * 2048 + c * 8, &sK[slotBase * 8]);
            load_lds16(Vbase + (size_t)rw * 2048 + t0 + c * 8, &sV[slotBase * 8]);
        }
        __syncthreads();

        f32x16 sc[4];
#pragma unroll
        for (int mt = 0; mt < 4; mt++) {
#pragma unroll
            for (int g = 0; g < 16; g++) sc[mt][g] = 0.f;
#pragma unroll
            for (int kc = 0; kc < 8; kc++) {
                bf16x8 kf = *(const bf16x8*)(
                    sK + (mt * 32 + l31) * 128 + (((kc * 2 + half) ^ swzA)) * 8);
                sc[mt] = __builtin_amdgcn_mfma_f32_32x32x16_bf16(kf, qf[kc], sc[mt], 0, 0, 0);
            }
        }

        if (kt == nkt - 1) {
#pragma unroll
            for (int mt = 0; mt < 4; mt++)
#pragma unroll
                for (int g = 0; g < 16; g++) {
                    int key = t0 + mt * 32 + 16 * ((g >> 3) & 1) + 8 * half +
                              4 * ((g >> 2) & 1) + (g & 3);
                    if (key > query_g) sc[mt][g] = -INFINITY;
                }
        }

        float mt_ = -INFINITY;
#pragma unroll
        for (int mt = 0; mt < 4; mt++)
#pragma unroll
            for (int g = 0; g < 16; g++) mt_ = fmaxf(mt_, sc[mt][g]);
        mt_ = fmaxf(mt_, __shfl_xor(mt_, 32));
        const float mn = fmaxf(m_i, mt_);
        const float alpha = __builtin_amdgcn_exp2f(m_i - mn);
        m_i = mn;
        float rs = 0.f;
#pragma unroll
        for (int mt = 0; mt < 4; mt++)
#pragma unroll
            for (int g = 0; g < 16; g++) {
                float pv = __builtin_amdgcn_exp2f(sc[mt][g] - mn);
                sc[mt][g] = pv;
                rs += pv;
            }
        l_i = l_i * alpha + rs;
#pragma unroll
        for (int ht = 0; ht < 4; ht++)
#pragma unroll
            for (int g = 0; g < 16; g++) accO[ht][g] *= alpha;

        unsigned pk[4][8];
#pragma unroll
        for (int mt = 0; mt < 4; mt++)
#pragma unroll
            for (int p = 0; p < 8; p++)
                pk[mt][p] = pack_bf16x2(sc[mt][2 * p], sc[mt][2 * p + 1]);

#pragma unroll
        for (int kc = 0; kc < 8; kc++) {
            union { unsigned u[4]; bf16x8 v; } pf;
            const int mtk = kc >> 1, base = 4 * (kc & 1);
#pragma unroll
            for (int jj = 0; jj < 4; jj++) pf.u[jj] = pk[mtk][base + jj];
#pragma unroll
            for (int ht = 0; ht < 4; ht++) {
                bf16x8 vf = *(const bf16x8*)(
                    sV + (ht * 32 + l31) * 128 + (((kc * 2 + half) ^ swzA)) * 8);
                accO[ht] = __builtin_amdgcn_mfma_f32_32x32x16_bf16(vf, pf.v, accO[ht], 0, 0, 0);
            }
        }
    }

    const float linv = 1.f / (l_i + __shfl_xor(l_i, 32));
    bf16* Orow = O + (size_t)(bb * 2048 + qb + query_l) * 2048 + head * 128;
#pragma unroll
    for (int ht = 0; ht < 4; ht++)
#pragma unroll
        for (int u = 0; u < 4; u++) {
            bf16v4 o4;
#pragma unroll
            for (int i = 0; i < 4; i++) o4[i] = (bf16)(accO[ht][4 * u + i] * linv);
            *(bf16v4*)(Orow + ht * 32 + 8 * u + 4 * half) = o4;
        }
}

// ---------------------------------------------------------------------------
// wo GEMM (prefill out, fp32 nontemporal stores) + folded decode combine
// (bid>=512: 32 blocks, one wave each, barrier-free).
__global__ __launch_bounds__(256) void k_gemm_o(
    const bf16* __restrict__ A, const bf16* __restrict__ Bt,
    float* __restrict__ Cf,
    const bf16* __restrict__ q1, const bf16* __restrict__ k1,
    const bf16* __restrict__ v1, const float* __restrict__ pm,
    const float* __restrict__ pl, const float* __restrict__ pacc,
    bf16* __restrict__ o1) {
    const int K = 2048, N = 2048;
    __shared__ __align__(16) bf16 sA[128 * 32];
    __shared__ __align__(16) bf16 sB[128 * 32];
    const int bid = blockIdx.x;
    const int tid = threadIdx.x;
    if (bid >= 512) {
        if (tid >= 64) return;
        const int r = bid - 512;
        const int head = r & 15, b = r >> 4;
        const size_t off = (size_t)b * 2048 + head * 128;
        const int lane = tid;
        float d = (float)q1[off + lane] * (float)k1[off + lane] +
                  (float)q1[off + 64 + lane] * (float)k1[off + 64 + lane];
#pragma unroll
        for (int o = 1; o <= 32; o <<= 1) d += __shfl_xor(d, o);
        const float sn = d;  // all lanes
        const int base = (b * 16 + head) * 8;
        float M = sn;
#pragma unroll
        for (int sp = 0; sp < 8; sp++) M = fmaxf(M, pm[base + sp]);
        const float wn = __builtin_amdgcn_exp2f(sn - M);
#pragma unroll
        for (int hh = 0; hh < 2; hh++) {
            const int h = lane + hh * 64;
            float l = wn;
            float o = wn * (float)v1[off + h];
#pragma unroll
            for (int sp = 0; sp < 8; sp++) {
                float w = __builtin_amdgcn_exp2f(pm[base + sp] - M);
                l += pl[base + sp] * w;
                o += pacc[(size_t)(base + sp) * 128 + h] * w;
            }
            o1[off + h] = (bf16)(o / l);
        }
        return;
    }
    const int wave = tid >> 6, lane = tid & 63;
    const int quad = lane >> 4, l15 = lane & 15;
    const int rsw = (l15 >> 1) & 3;
    const int wm = (wave >> 1) * 64, wn2 = (wave & 1) * 64;
    const int m0 = (bid & 31) * 128, n0 = (bid >> 5) * 128;

    f32x4 acc[4][4];
#pragma unroll
    for (int a = 0; a < 4; a++)
#pragma unroll
        for (int c = 0; c < 4; c++)
#pragma unroll
            for (int r = 0; r < 4; r++) acc[a][c][r] = 0.f;

    for (int k0 = 0; k0 < K; k0 += 32) {
        __syncthreads();
#pragma unroll
        for (int i = 0; i < 2; i++) {
            const int slotBase = wave * 128 + i * 64;
            const int slot = slotBase + lane;
            const int row = slot >> 2, cp = slot & 3;
            const int g = cp ^ ((row >> 1) & 3);
            load_lds16(A + (size_t)(m0 + row) * K + k0 + g * 8, &sA[slotBase * 8]);
            load_lds16(Bt + (size_t)(n0 + row) * K + k0 + g * 8, &sB[slotBase * 8]);
        }
        __syncthreads();
        bf16x8 af[4], bfr[4];
#pragma unroll
        for (int t = 0; t < 4; t++) {
            af[t] = *(const bf16x8*)(sA + (wm + t * 16 + l15) * 32 + (quad ^ rsw) * 8);
            bfr[t] = *(const bf16x8*)(sB + (wn2 + t * 16 + l15) * 32 + (quad ^ rsw) * 8);
        }
#pragma unroll
        for (int mi = 0; mi < 4; mi++)
#pragma unroll
            for (int ni = 0; ni < 4; ni++)
                acc[mi][ni] = __builtin_amdgcn_mfma_f32_16x16x32_bf16(
                    af[mi], bfr[ni], acc[mi][ni], 0, 0, 0);
    }
#pragma unroll
    for (int mi = 0; mi < 4; mi++)
#pragma unroll
        for (int ni = 0; ni < 4; ni++)
#pragma unroll
            for (int r = 0; r < 4; r++) {
                int row = m0 + wm + mi * 16 + quad * 4 + r;
                int col = n0 + wn2 + ni * 16 + l15;
                __builtin_nontemporal_store(acc[mi][ni][r], &Cf[(size_t)row * N + col]);
            }
}

// Final decode output GEMV (fp32 out): grid (512, B), 256 thr.
__global__ void k_gemv_o(const bf16* __restrict__ x, const bf16* __restrict__ W,
                         float* __restrict__ y) {
    const int wave = threadIdx.x >> 6, lane = threadIdx.x & 63;
    const int n = blockIdx.x * 4 + wave;
    const int b = blockIdx.y;
    const bf16* xr = x + (size_t)b * 2048;
    const bf16* wr = W + (size_t)n * 2048;
    float s = 0.f;
#pragma unroll
    for (int i = 0; i < 4; i++) {
        int k = i * 512 + lane * 8;
        bf16v8 xv = *(const bf16v8*)(xr + k);
        bf16v8 wv = *(const bf16v8*)(wr + k);
#pragma unroll
        for (int j = 0; j < 8; j++) s += (float)xv[j] * (float)wv[j];
    }
#pragma unroll
    for (int off = 1; off <= 32; off <<= 1) s += __shfl_xor(s, off);
    if (lane == 0) y[(size_t)b * 2048 + n] = s;
}

// ---------------------------------------------------------------------------
extern "C" void kernel_launch(void* const* d_in, const int* in_sizes, int n_in,
                              void* d_out, int out_size, void* d_ws, size_t ws_size,
                              hipStream_t stream) {
    const float* x  = (const float*)d_in[0];   // [2,2048,2048]
    const float* xn = (const float*)d_in[1];   // [2,1,2048]
    const float* wq = (const float*)d_in[2];   // [2048,16,128]
    const float* wk = (const float*)d_in[3];
    const float* wv = (const float*)d_in[4];
    const float* wo = (const float*)d_in[5];
    float* out = (float*)d_out;

    char* p = (char*)d_ws;
    auto alloc = [&](size_t bytes) {
        char* r = p;
        p += (bytes + 255) & ~(size_t)255;
        return r;
    };
    bf16* xb  = (bf16*)alloc((size_t)4096 * 2048 * 2);
    bf16* xnb = (bf16*)alloc((size_t)2 * 2048 * 2);
    // wqT/wkT/wvT contiguous: fused GEMM reads them as one [6144][2048] matrix
    bf16* wqT = (bf16*)alloc((size_t)2048 * 2048 * 2);
    bf16* wkT = (bf16*)alloc((size_t)2048 * 2048 * 2);
    bf16* wvT = (bf16*)alloc((size_t)2048 * 2048 * 2);
    (void)wkT; (void)wvT;
    bf16* wob = (bf16*)alloc((size_t)2048 * 2048 * 2);
    bf16* Qb  = (bf16*)alloc((size_t)4096 * 2048 * 2);
    bf16* Kb  = (bf16*)alloc((size_t)4096 * 2048 * 2);
    bf16* Vtb = (bf16*)alloc((size_t)4096 * 2048 * 2);
    bf16* AOb = (bf16*)alloc((size_t)4096 * 2048 * 2);
    bf16* q1b = (bf16*)alloc((size_t)2 * 2048 * 2);
    bf16* k1b = (bf16*)alloc((size_t)2 * 2048 * 2);
    bf16* v1b = (bf16*)alloc((size_t)2 * 2048 * 2);
    bf16* o1b = (bf16*)alloc((size_t)2 * 2048 * 2);
    float* pm   = (float*)alloc(256 * 4);
    float* pl   = (float*)alloc(256 * 4);
    float* pacc = (float*)alloc((size_t)256 * 128 * 4);

    // 1/sqrt(128) * log2(e): softmax runs in exp2 domain
    const float qscale = 0.08838834764831845f * 1.4426950408889634f;

    k_prep<<<24580, 256, 0, stream>>>(x, xn, wq, wk, wv, wo, xb, xnb, wqT, wob, qscale);
    k_gemm_qkv<<<1552, 256, 0, stream>>>(xb, wqT, Qb, Kb, Vtb, xnb, q1b, k1b, v1b);
    k_attn<<<768, 256, 0, stream>>>(Qb, Kb, Vtb, AOb, q1b, pm, pl, pacc);
    k_gemm_o<<<544, 256, 0, stream>>>(AOb, wob, out, q1b, k1b, v1b, pm, pl, pacc, o1b);
    k_gemv_o<<<dim3(512, 2), 256, 0, stream>>>(o1b, wob, out + 8388608);
}

// Round 7
// 377.324 us; speedup vs baseline: 1.2175x; 1.2175x over previous
//
#include <hip/hip_runtime.h>
#include <cmath>

typedef __bf16 bf16;
typedef short bf16x8 __attribute__((ext_vector_type(8)));   // MFMA A/B fragment (bf16 bit patterns)
typedef __bf16 bf16v8 __attribute__((ext_vector_type(8)));  // arithmetic bf16 vector
typedef __bf16 bf16v4 __attribute__((ext_vector_type(4)));
typedef float f32x4 __attribute__((ext_vector_type(4)));
typedef float f32x16 __attribute__((ext_vector_type(16)));

// async global->LDS, 16B per lane. LDS base must be wave-uniform; HW adds lane*16.
__device__ __forceinline__ void load_lds16(const void* g, void* l) {
    __builtin_amdgcn_global_load_lds(
        (const __attribute__((address_space(1))) void*)g,
        (__attribute__((address_space(3))) void*)l, 16, 0, 0);
}

__device__ __forceinline__ unsigned pack_bf16x2(float a, float b) {
    union { bf16 h[2]; unsigned u; } t;
    t.h[0] = (bf16)a;
    t.h[1] = (bf16)b;
    return t.u;
}

// ---------------------------------------------------------------------------
// Fused prep: 1D grid, block ranges:
// [0,8192)        x f32 -> xb bf16          (8388608 elems)
// [8192,20480)    wq/wk/wv transpose+cvt -> wT[z]   (3 x 64x64 tiles)
// [20480,24576)   wo f32 -> wob bf16        (4194304 elems)
// [24576,24580)   xn -> xnb                 (4096 elems)
__global__ __launch_bounds__(256) void k_prep(
    const float* __restrict__ x, const float* __restrict__ xn,
    const float* __restrict__ wq, const float* __restrict__ wk,
    const float* __restrict__ wv, const float* __restrict__ wo,
    bf16* __restrict__ xb, bf16* __restrict__ xnb, bf16* __restrict__ wT,
    bf16* __restrict__ wob, float qscale) {
    __shared__ float tile[32][33];
    const int bid = blockIdx.x, tid = threadIdx.x;
    if (bid < 8192) {
        int i = bid * 1024 + tid * 4;
        float4 v = *(const float4*)(x + i);
        bf16v4 o;
        o[0] = (bf16)v.x; o[1] = (bf16)v.y; o[2] = (bf16)v.z; o[3] = (bf16)v.w;
        *(bf16v4*)(xb + i) = o;
    } else if (bid < 20480) {
        const int r = bid - 8192;
        const int z = r >> 12, rr = r & 4095;
        const float* w = z == 0 ? wq : z == 1 ? wk : wv;
        bf16* wt = wT + (size_t)z * 4194304;
        const float scale = z == 0 ? qscale : 1.f;
        const int tx = tid & 31, ty = tid >> 5;  // 32 x 8
        const int k0 = (rr & 63) * 32, n0 = (rr >> 6) * 32;
#pragma unroll
        for (int i = 0; i < 4; i++) {
            int kk = ty + i * 8;
            tile[kk][tx] = w[(size_t)(k0 + kk) * 2048 + n0 + tx];
        }
        __syncthreads();
#pragma unroll
        for (int i = 0; i < 4; i++) {
            int nn = ty + i * 8;
            wt[(size_t)(n0 + nn) * 2048 + k0 + tx] = (bf16)(tile[tx][nn] * scale);
        }
    } else if (bid < 24576) {
        int i = (bid - 20480) * 1024 + tid * 4;
        float4 v = *(const float4*)(wo + i);
        bf16v4 o;
        o[0] = (bf16)v.x; o[1] = (bf16)v.y; o[2] = (bf16)v.z; o[3] = (bf16)v.w;
        *(bf16v4*)(wob + i) = o;
    } else {
        int i = (bid - 24576) * 1024 + tid * 4;
        float4 v = *(const float4*)(xn + i);
        bf16v4 o;
        o[0] = (bf16)v.x; o[1] = (bf16)v.y; o[2] = (bf16)v.z; o[3] = (bf16)v.w;
        *(bf16v4*)(xnb + i) = o;
    }
}

// ---------------------------------------------------------------------------
// Fused QKV GEMM + decode QKV GEMV.
// bid<1536: 128x128 tile GEMM A[4096][2048] x Bt[6144][2048]^T (m-fastest).
//   LDS chunk-swizzled (chunk = quad ^ ((row>>1)&3)) -> conflict-free b128.
//   n0<2048 -> Q; <4096 -> K; else V written transposed to Vt[b][nh][s].
// bid>=1536 (1536 blocks): decode GEMV, ONE row per wave (6144 rows, both
//   batches per wave) -- fully parallel, no serial tail (R6 post-mortem).
__global__ __launch_bounds__(256) void k_gemm_qkv(
    const bf16* __restrict__ A, const bf16* __restrict__ Bt,
    bf16* __restrict__ Qo, bf16* __restrict__ Ko, bf16* __restrict__ Vto,
    const bf16* __restrict__ xnb, bf16* __restrict__ q1,
    bf16* __restrict__ k1, bf16* __restrict__ v1) {
    const int K = 2048;
    __shared__ __align__(16) bf16 sA[128 * 32];
    __shared__ __align__(16) bf16 sB[128 * 32];
    const int bid = blockIdx.x;
    const int tid = threadIdx.x;
    if (bid >= 1536) {
        // ---- decode GEMV: one (z,n) row per wave, both b at once ----
        const int wave = tid >> 6, lane = tid & 63;
        const int u = (bid - 1536) * 4 + wave;  // 0..6143
        const int z = u >> 11, n = u & 2047;
        const bf16* wr = Bt + (size_t)z * 4194304 + (size_t)n * 2048;
        float s0 = 0.f, s1 = 0.f;
#pragma unroll
        for (int i = 0; i < 4; i++) {
            int k = i * 512 + lane * 8;
            bf16v8 wv8 = *(const bf16v8*)(wr + k);
            bf16v8 x0 = *(const bf16v8*)(xnb + k);
            bf16v8 x1 = *(const bf16v8*)(xnb + 2048 + k);
#pragma unroll
            for (int j = 0; j < 8; j++) {
                float wj = (float)wv8[j];
                s0 += (float)x0[j] * wj;
                s1 += (float)x1[j] * wj;
            }
        }
#pragma unroll
        for (int off = 1; off <= 32; off <<= 1) {
            s0 += __shfl_xor(s0, off);
            s1 += __shfl_xor(s1, off);
        }
        if (lane == 0) {
            bf16* y = z == 0 ? q1 : z == 1 ? k1 : v1;
            y[n] = (bf16)s0;
            y[2048 + n] = (bf16)s1;
        }
        return;
    }
    const int wave = tid >> 6, lane = tid & 63;
    const int quad = lane >> 4, l15 = lane & 15;
    const int rsw = (l15 >> 1) & 3;  // == (row>>1)&3 for all frag rows
    const int wm = (wave >> 1) * 64, wn = (wave & 1) * 64;
    const int m0 = (bid & 31) * 128, n0 = (bid >> 5) * 128;

    f32x4 acc[4][4];
#pragma unroll
    for (int a = 0; a < 4; a++)
#pragma unroll
        for (int c = 0; c < 4; c++)
#pragma unroll
            for (int r = 0; r < 4; r++) acc[a][c][r] = 0.f;

    for (int k0 = 0; k0 < K; k0 += 32) {
        __syncthreads();
#pragma unroll
        for (int i = 0; i < 2; i++) {
            const int slotBase = wave * 128 + i * 64;
            const int slot = slotBase + lane;
            const int row = slot >> 2, cp = slot & 3;
            const int g = cp ^ ((row >> 1) & 3);  // swizzle: LDS chunk cp holds global chunk g
            load_lds16(A + (size_t)(m0 + row) * K + k0 + g * 8, &sA[slotBase * 8]);
            load_lds16(Bt + (size_t)(n0 + row) * K + k0 + g * 8, &sB[slotBase * 8]);
        }
        __syncthreads();
        bf16x8 af[4], bfr[4];
#pragma unroll
        for (int t = 0; t < 4; t++) {
            af[t] = *(const bf16x8*)(sA + (wm + t * 16 + l15) * 32 + (quad ^ rsw) * 8);
            bfr[t] = *(const bf16x8*)(sB + (wn + t * 16 + l15) * 32 + (quad ^ rsw) * 8);
        }
#pragma unroll
        for (int mi = 0; mi < 4; mi++)
#pragma unroll
            for (int ni = 0; ni < 4; ni++)
                acc[mi][ni] = __builtin_amdgcn_mfma_f32_16x16x32_bf16(
                    af[mi], bfr[ni], acc[mi][ni], 0, 0, 0);
    }

    if (n0 < 4096) {
        bf16* Co = n0 < 2048 ? Qo : Ko;
        const int nb = n0 & 2047;
#pragma unroll
        for (int mi = 0; mi < 4; mi++)
#pragma unroll
            for (int ni = 0; ni < 4; ni++)
#pragma unroll
                for (int r = 0; r < 4; r++) {
                    int row = m0 + wm + mi * 16 + quad * 4 + r;
                    int col = nb + wn + ni * 16 + l15;
                    Co[(size_t)row * 2048 + col] = (bf16)acc[mi][ni][r];
                }
    } else {
        const int nb = n0 - 4096;
        const int b = m0 >> 11, s0v = m0 & 2047;
#pragma unroll
        for (int mi = 0; mi < 4; mi++)
#pragma unroll
            for (int ni = 0; ni < 4; ni++) {
                const int nh = nb + wn + ni * 16 + l15;
                bf16v4 o4;
#pragma unroll
                for (int r = 0; r < 4; r++) o4[r] = (bf16)acc[mi][ni][r];
                *(bf16v4*)(Vto + (size_t)(b * 2048 + nh) * 2048 + s0v + wm +
                           mi * 16 + quad * 4) = o4;
            }
    }
}

// ---------------------------------------------------------------------------
// Flash-style causal prefill attention v5 (kappa-permuted keys) + folded
// split-K decode phase 1 (bid>=512).
__global__ __launch_bounds__(256, 2) void k_attn(
    const bf16* __restrict__ Q, const bf16* __restrict__ Kc,
    const bf16* __restrict__ Vt, bf16* __restrict__ O,
    const bf16* __restrict__ q1, float* __restrict__ pm,
    float* __restrict__ pl, float* __restrict__ pacc) {
    __shared__ __align__(16) bf16 sK[128 * 128];
    __shared__ __align__(16) bf16 sV[128 * 128];
    const int tid = threadIdx.x;

    if (blockIdx.x >= 512) {
        // ---- decode split-K phase 1: r -> (head, b, split), 256 keys ----
        __shared__ __align__(16) bf16 sq[128];
        __shared__ float scd[256];
        __shared__ float red[4];
        __shared__ float ph[256];
        const int r = blockIdx.x - 512;
        const int head = r & 15, b = (r >> 4) & 1, sp = r >> 5;
        const int s0 = sp * 256;
        const int lane = tid & 63, wave = tid >> 6;
        const int idx = (b * 16 + head) * 8 + sp;

        if (tid < 16)
            *(uint4*)(sq + tid * 8) =
                *(const uint4*)(q1 + (size_t)b * 2048 + head * 128 + tid * 8);
        __syncthreads();

        const bf16* kr = Kc + (size_t)(b * 2048 + s0 + tid) * 2048 + head * 128;
        float s = 0.f;
#pragma unroll
        for (int k = 0; k < 128; k += 8) {
            bf16v8 kv = *(const bf16v8*)(kr + k);
            bf16v8 qv = *(const bf16v8*)(sq + k);
#pragma unroll
            for (int j = 0; j < 8; j++) s += (float)qv[j] * (float)kv[j];
        }
        float m = s;
#pragma unroll
        for (int off = 1; off <= 32; off <<= 1) m = fmaxf(m, __shfl_xor(m, off));
        if (lane == 0) red[wave] = m;
        __syncthreads();
        const float gm = fmaxf(fmaxf(red[0], red[1]), fmaxf(red[2], red[3]));
        float p = __builtin_amdgcn_exp2f(s - gm);
        scd[tid] = p;
        float ls = p;
#pragma unroll
        for (int off = 1; off <= 32; off <<= 1) ls += __shfl_xor(ls, off);
        __syncthreads();
        if (lane == 0) red[wave] = ls;
        __syncthreads();
        if (tid == 0) {
            pm[idx] = gm;
            pl[idx] = red[0] + red[1] + red[2] + red[3];
        }
        const int h = tid & 127, halfk = tid >> 7;
        const bf16* vr =
            Vt + (size_t)(b * 2048 + head * 128 + h) * 2048 + s0 + halfk * 128;
        float acc = 0.f;
#pragma unroll
        for (int t = 0; t < 128; t += 8) {
            bf16v8 vv = *(const bf16v8*)(vr + t);
#pragma unroll
            for (int j = 0; j < 8; j++) acc += scd[halfk * 128 + t + j] * (float)vv[j];
        }
        ph[tid] = acc;
        __syncthreads();
        if (halfk == 0) pacc[(size_t)idx * 128 + h] = ph[tid] + ph[tid + 128];
        return;
    }

    const int wave = tid >> 6, lane = tid & 63;
    const int l31 = lane & 31, half = lane >> 5;
    const int lin = blockIdx.x;
    const int bb = lin >> 8;
    const int idx = lin & 255;
    const int T = bb ? (15 - (idx & 15)) : (idx & 15);
    const int head = idx >> 4;
    const int qb = T * 128;
    const int nkt = T + 1;

    const bf16* Kbase = Kc + (size_t)(bb * 2048) * 2048 + head * 128;
    const bf16* Vbase = Vt + (size_t)(bb * 2048 + head * 128) * 2048;
    const int swzA = l31 & 7;

    const int query_l = wave * 32 + l31;
    const bf16* Qrow = Q + (size_t)(bb * 2048 + qb + query_l) * 2048 + head * 128;
    bf16x8 qf[8];
#pragma unroll
    for (int kc = 0; kc < 8; kc++)
        qf[kc] = *(const bf16x8*)(Qrow + kc * 16 + half * 8);

    f32x16 accO[4];
#pragma unroll
    for (int ht = 0; ht < 4; ht++)
#pragma unroll
        for (int g = 0; g < 16; g++) accO[ht][g] = 0.f;
    float m_i = -INFINITY, l_i = 0.f;
    const int query_g = qb + query_l;

    for (int kt = 0; kt < nkt; ++kt) {
        const int t0 = kt * 128;
        __syncthreads();
#pragma unroll
        for (int i = 0; i < 8; ++i) {
            const int slotBase = wave * 512 + i * 64;
            const int slot = slotBase + lane;
            const int rw = slot >> 4, cp = slot & 15;
            const int c = cp ^ (rw & 7);
            const int krw = (rw & ~12) | ((rw & 4) << 1) | ((rw & 8) >> 1);  // kappa
            load_lds16(Kbase + (size_t)(t0 + krw) * 2048 + c * 8, &sK[slotBase * 8]);
            load_lds16(Vbase + (size_t)rw * 2048 + t0 + c * 8, &sV[slotBase * 8]);
        }
        __syncthreads();

        f32x16 sc[4];
#pragma unroll
        for (int mt = 0; mt < 4; mt++) {
#pragma unroll
            for (int g = 0; g < 16; g++) sc[mt][g] = 0.f;
#pragma unroll
            for (int kc = 0; kc < 8; kc++) {
                bf16x8 kf = *(const bf16x8*)(
                    sK + (mt * 32 + l31) * 128 + (((kc * 2 + half) ^ swzA)) * 8);
                sc[mt] = __builtin_amdgcn_mfma_f32_32x32x16_bf16(kf, qf[kc], sc[mt], 0, 0, 0);
            }
        }

        if (kt == nkt - 1) {
#pragma unroll
            for (int mt = 0; mt < 4; mt++)
#pragma unroll
                for (int g = 0; g < 16; g++) {
                    int key = t0 + mt * 32 + 16 * ((g >> 3) & 1) + 8 * half +
                              4 * ((g >> 2) & 1) + (g & 3);
                    if (key > query_g) sc[mt][g] = -INFINITY;
                }
        }

        float mt_ = -INFINITY;
#pragma unroll
        for (int mt = 0; mt < 4; mt++)
#pragma unroll
            for (int g = 0; g < 16; g++) mt_ = fmaxf(mt_, sc[mt][g]);
        mt_ = fmaxf(mt_, __shfl_xor(mt_, 32));
        const float mn = fmaxf(m_i, mt_);
        const float alpha = __builtin_amdgcn_exp2f(m_i - mn);
        m_i = mn;
        float rs = 0.f;
#pragma unroll
        for (int mt = 0; mt < 4; mt++)
#pragma unroll
            for (int g = 0; g < 16; g++) {
                float pv = __builtin_amdgcn_exp2f(sc[mt][g] - mn);
                sc[mt][g] = pv;
                rs += pv;
            }
        l_i = l_i * alpha + rs;
#pragma unroll
        for (int ht = 0; ht < 4; ht++)
#pragma unroll
            for (int g = 0; g < 16; g++) accO[ht][g] *= alpha;

        unsigned pk[4][8];
#pragma unroll
        for (int mt = 0; mt < 4; mt++)
#pragma unroll
            for (int p = 0; p < 8; p++)
                pk[mt][p] = pack_bf16x2(sc[mt][2 * p], sc[mt][2 * p + 1]);

#pragma unroll
        for (int kc = 0; kc < 8; kc++) {
            union { unsigned u[4]; bf16x8 v; } pf;
            const int mtk = kc >> 1, base = 4 * (kc & 1);
#pragma unroll
            for (int jj = 0; jj < 4; jj++) pf.u[jj] = pk[mtk][base + jj];
#pragma unroll
            for (int ht = 0; ht < 4; ht++) {
                bf16x8 vf = *(const bf16x8*)(
                    sV + (ht * 32 + l31) * 128 + (((kc * 2 + half) ^ swzA)) * 8);
                accO[ht] = __builtin_amdgcn_mfma_f32_32x32x16_bf16(vf, pf.v, accO[ht], 0, 0, 0);
            }
        }
    }

    const float linv = 1.f / (l_i + __shfl_xor(l_i, 32));
    bf16* Orow = O + (size_t)(bb * 2048 + qb + query_l) * 2048 + head * 128;
#pragma unroll
    for (int ht = 0; ht < 4; ht++)
#pragma unroll
        for (int u = 0; u < 4; u++) {
            bf16v4 o4;
#pragma unroll
            for (int i = 0; i < 4; i++) o4[i] = (bf16)(accO[ht][4 * u + i] * linv);
            *(bf16v4*)(Orow + ht * 32 + 8 * u + 4 * half) = o4;
        }
}

// ---------------------------------------------------------------------------
// wo GEMM (prefill out, fp32 nontemporal stores) + folded decode combine
// (bid>=512: 32 blocks, one wave each, barrier-free).
__global__ __launch_bounds__(256) void k_gemm_o(
    const bf16* __restrict__ A, const bf16* __restrict__ Bt,
    float* __restrict__ Cf,
    const bf16* __restrict__ q1, const bf16* __restrict__ k1,
    const bf16* __restrict__ v1, const float* __restrict__ pm,
    const float* __restrict__ pl, const float* __restrict__ pacc,
    bf16* __restrict__ o1) {
    const int K = 2048, N = 2048;
    __shared__ __align__(16) bf16 sA[128 * 32];
    __shared__ __align__(16) bf16 sB[128 * 32];
    const int bid = blockIdx.x;
    const int tid = threadIdx.x;
    if (bid >= 512) {
        if (tid >= 64) return;
        const int r = bid - 512;
        const int head = r & 15, b = r >> 4;
        const size_t off = (size_t)b * 2048 + head * 128;
        const int lane = tid;
        float d = (float)q1[off + lane] * (float)k1[off + lane] +
                  (float)q1[off + 64 + lane] * (float)k1[off + 64 + lane];
#pragma unroll
        for (int o = 1; o <= 32; o <<= 1) d += __shfl_xor(d, o);
        const float sn = d;  // all lanes
        const int base = (b * 16 + head) * 8;
        float M = sn;
#pragma unroll
        for (int sp = 0; sp < 8; sp++) M = fmaxf(M, pm[base + sp]);
        const float wn = __builtin_amdgcn_exp2f(sn - M);
#pragma unroll
        for (int hh = 0; hh < 2; hh++) {
            const int h = lane + hh * 64;
            float l = wn;
            float o = wn * (float)v1[off + h];
#pragma unroll
            for (int sp = 0; sp < 8; sp++) {
                float w = __builtin_amdgcn_exp2f(pm[base + sp] - M);
                l += pl[base + sp] * w;
                o += pacc[(size_t)(base + sp) * 128 + h] * w;
            }
            o1[off + h] = (bf16)(o / l);
        }
        return;
    }
    const int wave = tid >> 6, lane = tid & 63;
    const int quad = lane >> 4, l15 = lane & 15;
    const int rsw = (l15 >> 1) & 3;
    const int wm = (wave >> 1) * 64, wn2 = (wave & 1) * 64;
    const int m0 = (bid & 31) * 128, n0 = (bid >> 5) * 128;

    f32x4 acc[4][4];
#pragma unroll
    for (int a = 0; a < 4; a++)
#pragma unroll
        for (int c = 0; c < 4; c++)
#pragma unroll
            for (int r = 0; r < 4; r++) acc[a][c][r] = 0.f;

    for (int k0 = 0; k0 < K; k0 += 32) {
        __syncthreads();
#pragma unroll
        for (int i = 0; i < 2; i++) {
            const int slotBase = wave * 128 + i * 64;
            const int slot = slotBase + lane;
            const int row = slot >> 2, cp = slot & 3;
            const int g = cp ^ ((row >> 1) & 3);
            load_lds16(A + (size_t)(m0 + row) * K + k0 + g * 8, &sA[slotBase * 8]);
            load_lds16(Bt + (size_t)(n0 + row) * K + k0 + g * 8, &sB[slotBase * 8]);
        }
        __syncthreads();
        bf16x8 af[4], bfr[4];
#pragma unroll
        for (int t = 0; t < 4; t++) {
            af[t] = *(const bf16x8*)(sA + (wm + t * 16 + l15) * 32 + (quad ^ rsw) * 8);
            bfr[t] = *(const bf16x8*)(sB + (wn2 + t * 16 + l15) * 32 + (quad ^ rsw) * 8);
        }
#pragma unroll
        for (int mi = 0; mi < 4; mi++)
#pragma unroll
            for (int ni = 0; ni < 4; ni++)
                acc[mi][ni] = __builtin_amdgcn_mfma_f32_16x16x32_bf16(
                    af[mi], bfr[ni], acc[mi][ni], 0, 0, 0);
    }
#pragma unroll
    for (int mi = 0; mi < 4; mi++)
#pragma unroll
        for (int ni = 0; ni < 4; ni++)
#pragma unroll
            for (int r = 0; r < 4; r++) {
                int row = m0 + wm + mi * 16 + quad * 4 + r;
                int col = n0 + wn2 + ni * 16 + l15;
                __builtin_nontemporal_store(acc[mi][ni][r], &Cf[(size_t)row * N + col]);
            }
}

// Final decode output GEMV (fp32 out): grid (512, B), 256 thr.
__global__ void k_gemv_o(const bf16* __restrict__ x, const bf16* __restrict__ W,
                         float* __restrict__ y) {
    const int wave = threadIdx.x >> 6, lane = threadIdx.x & 63;
    const int n = blockIdx.x * 4 + wave;
    const int b = blockIdx.y;
    const bf16* xr = x + (size_t)b * 2048;
    const bf16* wr = W + (size_t)n * 2048;
    float s = 0.f;
#pragma unroll
    for (int i = 0; i < 4; i++) {
        int k = i * 512 + lane * 8;
        bf16v8 xv = *(const bf16v8*)(xr + k);
        bf16v8 wv = *(const bf16v8*)(wr + k);
#pragma unroll
        for (int j = 0; j < 8; j++) s += (float)xv[j] * (float)wv[j];
    }
#pragma unroll
    for (int off = 1; off <= 32; off <<= 1) s += __shfl_xor(s, off);
    if (lane == 0) y[(size_t)b * 2048 + n] = s;
}

// ---------------------------------------------------------------------------
extern "C" void kernel_launch(void* const* d_in, const int* in_sizes, int n_in,
                              void* d_out, int out_size, void* d_ws, size_t ws_size,
                              hipStream_t stream) {
    const float* x  = (const float*)d_in[0];   // [2,2048,2048]
    const float* xn = (const float*)d_in[1];   // [2,1,2048]
    const float* wq = (const float*)d_in[2];   // [2048,16,128]
    const float* wk = (const float*)d_in[3];
    const float* wv = (const float*)d_in[4];
    const float* wo = (const float*)d_in[5];
    float* out = (float*)d_out;

    char* p = (char*)d_ws;
    auto alloc = [&](size_t bytes) {
        char* r = p;
        p += (bytes + 255) & ~(size_t)255;
        return r;
    };
    bf16* xb  = (bf16*)alloc((size_t)4096 * 2048 * 2);
    bf16* xnb = (bf16*)alloc((size_t)2 * 2048 * 2);
    // wqT/wkT/wvT contiguous: fused GEMM reads them as one [6144][2048] matrix
    bf16* wqT = (bf16*)alloc((size_t)2048 * 2048 * 2);
    bf16* wkT = (bf16*)alloc((size_t)2048 * 2048 * 2);
    bf16* wvT = (bf16*)alloc((size_t)2048 * 2048 * 2);
    (void)wkT; (void)wvT;
    bf16* wob = (bf16*)alloc((size_t)2048 * 2048 * 2);
    bf16* Qb  = (bf16*)alloc((size_t)4096 * 2048 * 2);
    bf16* Kb  = (bf16*)alloc((size_t)4096 * 2048 * 2);
    bf16* Vtb = (bf16*)alloc((size_t)4096 * 2048 * 2);
    bf16* AOb = (bf16*)alloc((size_t)4096 * 2048 * 2);
    bf16* q1b = (bf16*)alloc((size_t)2 * 2048 * 2);
    bf16* k1b = (bf16*)alloc((size_t)2 * 2048 * 2);
    bf16* v1b = (bf16*)alloc((size_t)2 * 2048 * 2);
    bf16* o1b = (bf16*)alloc((size_t)2 * 2048 * 2);
    float* pm   = (float*)alloc(256 * 4);
    float* pl   = (float*)alloc(256 * 4);
    float* pacc = (float*)alloc((size_t)256 * 128 * 4);

    // 1/sqrt(128) * log2(e): softmax runs in exp2 domain
    const float qscale = 0.08838834764831845f * 1.4426950408889634f;

    k_prep<<<24580, 256, 0, stream>>>(x, xn, wq, wk, wv, wo, xb, xnb, wqT, wob, qscale);
    k_gemm_qkv<<<3072, 256, 0, stream>>>(xb, wqT, Qb, Kb, Vtb, xnb, q1b, k1b, v1b);
    k_attn<<<768, 256, 0, stream>>>(Qb, Kb, Vtb, AOb, q1b, pm, pl, pacc);
    k_gemm_o<<<544, 256, 0, stream>>>(AOb, wob, out, q1b, k1b, v1b, pm, pl, pacc, o1b);
    k_gemv_o<<<dim3(512, 2), 256, 0, stream>>>(o1b, wob, out + 8388608);
}